// Round 6
// baseline (262.754 us; speedup 1.0000x reference)
//
#include <hip/hip_runtime.h>
#include <cmath>

#define S_LEN 2048
#define EMB   1024
#define NHEAD 16
#define DHEAD 64
#define PIT   72   // LDS pitch (ushorts): 144B = 16B-aligned, worst 2-way bank alias (free per m136)

typedef __attribute__((ext_vector_type(8))) short bf16x8;
typedef __attribute__((ext_vector_type(4))) short bf16x4;
typedef __attribute__((ext_vector_type(4))) float f32x4;

// v_mfma_f32_16x16x16_bf16 (gfx90a-lineage builtin; instruction present on gfx950).
// Unconditional call passes host pass via deferred diagnostics (proven in round 5).
#define MFMA16(a,b,c) __builtin_amdgcn_mfma_f32_16x16x16bf16_1k(a,b,c,0,0,0)

__device__ __forceinline__ unsigned short f2bf(float f){
    union { float f; unsigned u; } v; v.f = f;
    unsigned r = v.u + 0x7fffu + ((v.u >> 16) & 1u);
    return (unsigned short)(r >> 16);
}

__device__ __forceinline__ unsigned pk2bf(float a, float b){
#if __has_builtin(__builtin_amdgcn_cvt_pk_bf16_f32)
    typedef __attribute__((ext_vector_type(2))) __bf16 bf2;
    bf2 r = __builtin_amdgcn_cvt_pk_bf16_f32(a, b);
    return *(unsigned*)&r;
#else
    return (unsigned)f2bf(a) | ((unsigned)f2bf(b) << 16);
#endif
}

__device__ __forceinline__ float fast_exp2(float x){
#if __has_builtin(__builtin_amdgcn_exp2f)
    return __builtin_amdgcn_exp2f(x);
#else
    return exp2f(x);
#endif
}

__device__ __forceinline__ float fast_rcp(float x){
#if __has_builtin(__builtin_amdgcn_rcpf)
    return __builtin_amdgcn_rcpf(x);
#else
    return 1.0f / x;
#endif
}

// ---------------- fused prep: range-dispatched over blockIdx.x ----------------
// [0,4096):     Q (prescaled exp2-domain) + K -> bf16 [N,H,S,D]
// [4096,5120):  V -> bf16 transposed [N,H,D,S]
// [5120,6144):  W -> bf16
// [6144,7168):  mask int32 -> 1 BIT per element, Mb[n][q][k/32] uint32 (1 MB, L2-resident)
__global__ void prep_all(const float* __restrict__ q, const float* __restrict__ k,
                         const float* __restrict__ v, const int* __restrict__ mask,
                         const float* __restrict__ W,
                         unsigned short* __restrict__ Qb, unsigned short* __restrict__ Kb,
                         unsigned short* __restrict__ Vt, unsigned short* __restrict__ Wb,
                         unsigned* __restrict__ Mb){
    __shared__ unsigned short tile[64*68];
    const int b = blockIdx.x, tid = threadIdx.x;
    if (b < 4096){
        const float SC = 0.045084220027780106f;   // log2(e)/32
        int base = (b*256 + tid) * 4;
        int e = base & (EMB - 1);
        int s = (base >> 10) & (S_LEN - 1);
        int n = base >> 21;
        int h = e >> 6, d = e & 63;
        int dst = ((n*NHEAD + h)*S_LEN + s)*DHEAD + d;
        float4 qv = *(const float4*)(q + base);
        float4 kv = *(const float4*)(k + base);
        uint2 qp, kp;
        qp.x = pk2bf(qv.x*SC, qv.y*SC);
        qp.y = pk2bf(qv.z*SC, qv.w*SC);
        kp.x = pk2bf(kv.x, kv.y);
        kp.y = pk2bf(kv.z, kv.w);
        *(uint2*)(Qb + dst) = qp;
        *(uint2*)(Kb + dst) = kp;
    } else if (b < 5120){
        int idx = b - 4096;
        int st = idx & 31, h = (idx >> 5) & 15, n = idx >> 9;
        int sbase = st * 64;
#pragma unroll
        for (int i = 0; i < 4; i++){
            int c = tid + i*256;
            int srow = c >> 4, c4 = (c & 15) * 4;
            float4 x = *(const float4*)(v + (n*S_LEN + sbase + srow)*EMB + h*DHEAD + c4);
            uint2 p;
            p.x = pk2bf(x.x, x.y);
            p.y = pk2bf(x.z, x.w);
            *(uint2*)&tile[srow*68 + c4] = p;
        }
        __syncthreads();
#pragma unroll
        for (int i = 0; i < 2; i++){
            int c = tid + i*256;
            int d = c >> 3, s8 = (c & 7) * 8;
            unsigned u0 = (unsigned)tile[(s8+0)*68 + d] | ((unsigned)tile[(s8+1)*68 + d] << 16);
            unsigned u1 = (unsigned)tile[(s8+2)*68 + d] | ((unsigned)tile[(s8+3)*68 + d] << 16);
            unsigned u2 = (unsigned)tile[(s8+4)*68 + d] | ((unsigned)tile[(s8+5)*68 + d] << 16);
            unsigned u3 = (unsigned)tile[(s8+6)*68 + d] | ((unsigned)tile[(s8+7)*68 + d] << 16);
            uint4 pk; pk.x = u0; pk.y = u1; pk.z = u2; pk.w = u3;
            *(uint4*)(Vt + ((n*NHEAD + h)*DHEAD + d)*S_LEN + sbase + s8) = pk;
        }
    } else if (b < 6144){
        int base = ((b - 5120)*256 + tid) * 4;
        float4 x = *(const float4*)(W + base);
        uint2 p;
        p.x = pk2bf(x.x, x.y);
        p.y = pk2bf(x.z, x.w);
        *(uint2*)(Wb + base) = p;
    } else {
        int u = (b - 6144)*256 + tid;                 // [0, 262144)
        const int4* m4 = (const int4*)mask + (size_t)u*8;
        unsigned w = 0;
#pragma unroll
        for (int i = 0; i < 8; i++){
            int4 m = m4[i];
            unsigned nib = (m.x ? 1u : 0u) | (m.y ? 2u : 0u) | (m.z ? 4u : 0u) | (m.w ? 8u : 0u);
            w |= nib << (i*4);
        }
        Mb[u] = w;
    }
}

// ---------------- flash attention: 64-row blocks, FULL K=2048, normalize in-kernel -------
// Split-K removed: each block owns 64 q-rows over the whole 2048 K, so accL is the COMPLETE
// row sum at the epilogue -> normalize in-register (accL[r] lives in the same lane as
// acc[dt][r]) and store bf16 normalized O directly. Kills the 32 MB fp32 partial buffers
// (gemm input 32->8 MB; per-XCD gemm working set now fits its 4 MB L2).
// K/V double-buffered in LDS -> ONE barrier per iter (writes to buf c while laggard waves
// still read buf c^1 are disjoint; next barrier orders write->read).
__global__ __launch_bounds__(256, 4) void flash_attn(
    const unsigned short* __restrict__ Qb, const unsigned short* __restrict__ Kb,
    const unsigned short* __restrict__ Vt, const unsigned* __restrict__ Mb,
    unsigned short* __restrict__ Ab){
    __shared__ unsigned short Kt[2][64*PIT];
    __shared__ unsigned short Vl[2][64*PIT];
    __shared__ uint2 mlut[16];

    const int tid = threadIdx.x;
    if (tid < 16){
        uint2 e;
        e.x = ((tid & 1) ? 0xFFFFu : 0u) | ((tid & 2) ? 0xFFFF0000u : 0u);
        e.y = ((tid & 4) ? 0xFFFFu : 0u) | ((tid & 8) ? 0xFFFF0000u : 0u);
        mlut[tid] = e;
    }

    // XCD-aware remap: each XCD owns 4 full (n,h) slices x 32 qt-blocks (K/V slice L2-local).
    const int flat = blockIdx.x + (blockIdx.y << 5) + (blockIdx.z << 9);
    const int xcd = flat & 7, idx = flat >> 3;        // idx [0,128)
    const int qt = idx & 31;
    const int sl = xcd + ((idx >> 5) << 3);           // [0,32)
    const int h = sl & 15, n = sl >> 4;

    const int wave = tid >> 6, lane = tid & 63, il = lane & 15, quad = lane >> 4;
    const int qbase = qt*64 + wave*16;

    const unsigned short* Qh = Qb + (n*NHEAD + h)*S_LEN*DHEAD;
    const unsigned short* Kh = Kb + (n*NHEAD + h)*S_LEN*DHEAD;
    const unsigned short* Vh = Vt + (n*NHEAD + h)*DHEAD*S_LEN;
    const unsigned* mr = Mb + (size_t)(n*S_LEN + qbase + il)*(S_LEN/32);

    const int srow = tid >> 3, scol = (tid & 7)*8;

    bf16x8 Qf[2];      // B-operand frags: n=il -> q row, k = quad*8+j -> d
#pragma unroll
    for (int ks = 0; ks < 2; ks++)
        Qf[ks] = *(const bf16x8*)(Qh + (qbase + il)*DHEAD + ks*32 + quad*8);

    f32x4 acc[4], accL;
    accL = (f32x4){0.f,0.f,0.f,0.f};
#pragma unroll
    for (int j = 0; j < 4; j++) acc[j] = (f32x4){0.f,0.f,0.f,0.f};
    const short onev = 0x3F80;   // bf16 1.0
    const bf16x4 ones4 = {onev,onev,onev,onev};
    const int q4 = quad*4;

    // prefetch tile 0 into registers
    uint4 kpre0 = *(const uint4*)(Kh + srow*DHEAD + scol);
    uint4 kpre1 = *(const uint4*)(Kh + (srow + 32)*DHEAD + scol);
    uint4 vpre0 = *(const uint4*)(Vh + srow*S_LEN + scol);
    uint4 vpre1 = *(const uint4*)(Vh + (srow + 32)*S_LEN + scol);

    int c = 0;
    for (int kb = 0; kb < S_LEN; kb += 64){
        // drain prefetch regs into LDS buf c (laggards still read buf c^1: disjoint)
        *(uint4*)&Kt[c][srow*PIT + scol]        = kpre0;
        *(uint4*)&Kt[c][(srow + 32)*PIT + scol] = kpre1;
        *(uint4*)&Vl[c][srow*PIT + scol]        = vpre0;
        *(uint4*)&Vl[c][(srow + 32)*PIT + scol] = vpre1;
        // issue next tile's loads BEFORE the barrier: cover = barrier + full compute phase
        if (kb + 64 < S_LEN){
            kpre0 = *(const uint4*)(Kh + (kb + 64 + srow)*DHEAD + scol);
            kpre1 = *(const uint4*)(Kh + (kb + 64 + srow + 32)*DHEAD + scol);
            vpre0 = *(const uint4*)(Vh + srow*S_LEN + kb + 64 + scol);
            vpre1 = *(const uint4*)(Vh + (srow + 32)*S_LEN + kb + 64 + scol);
        }
        __syncthreads();
        // mask bits for this 64-wide k-tile: 2 words per q-row, L2-resident
        uint2 w0 = *(const uint2*)(mr + (kb >> 5));

        // E^T = K.Q^T : A = K rows, B = Q rows. C: col=il -> q, row=quad*4+r -> k
        f32x4 e[4];
#pragma unroll
        for (int t = 0; t < 4; t++){
            bf16x8 kf0 = *(const bf16x8*)(&Kt[c][(t*16 + il)*PIT + quad*8]);
            bf16x8 kf1 = *(const bf16x8*)(&Kt[c][(t*16 + il)*PIT + 32 + quad*8]);
            f32x4 z = (f32x4){0.f,0.f,0.f,0.f};
            z    = __builtin_amdgcn_mfma_f32_16x16x32_bf16(kf0, Qf[0], z, 0, 0, 0);
            e[t] = __builtin_amdgcn_mfma_f32_16x16x32_bf16(kf1, Qf[1], z, 0, 0, 0);
        }
        // p = exp2(e); mask as AND on packed bf16 pairs. pw[t] is a ready K=16 A-frag.
        unsigned pw[4][2];
        {
            unsigned s0 = w0.x >> q4, s1 = w0.y >> q4;
            unsigned s0h = s0 >> 16, s1h = s1 >> 16;
#pragma unroll
            for (int t = 0; t < 4; t++){
                unsigned s = (t == 0) ? s0 : (t == 1) ? s0h : (t == 2) ? s1 : s1h;
                uint2 mw = mlut[s & 0xFu];
                float p0 = fast_exp2(e[t][0]);
                float p1 = fast_exp2(e[t][1]);
                float p2 = fast_exp2(e[t][2]);
                float p3 = fast_exp2(e[t][3]);
                pw[t][0] = pk2bf(p0, p1) & mw.x;
                pw[t][1] = pk2bf(p2, p3) & mw.y;
            }
        }
        // PV: O += P.V ; l += P.1 — K=16 MFMAs, P straight from registers
#pragma unroll
        for (int t = 0; t < 4; t++){
            uint2 u; u.x = pw[t][0]; u.y = pw[t][1];
            bf16x4 Pa = *(bf16x4*)&u;
            accL = MFMA16(Pa, ones4, accL);
#pragma unroll
            for (int dt = 0; dt < 4; dt++){
                bf16x4 Vf = *(const bf16x4*)(&Vl[c][(dt*16 + il)*PIT + t*16 + quad*4]);
                acc[dt] = MFMA16(Pa, Vf, acc[dt]);
            }
        }
        c ^= 1;
    }

    // epilogue: normalize in-register (accL[r] is the full row sum, same lane as acc[dt][r])
    // and store bf16 normalized O rows.
#pragma unroll
    for (int r = 0; r < 4; r++){
        float inv = fast_rcp(accL[r]);
        size_t row = (size_t)(n*S_LEN + qbase + quad*4 + r);
        unsigned short* dst = Ab + row*EMB + h*DHEAD + il;
#pragma unroll
        for (int dt = 0; dt < 4; dt++)
            dst[dt*16] = f2bf(acc[dt][r]*inv);
    }
}

// ---------------- output GEMM: out = Ab.W^T + b (A already normalized bf16) --------------
// 64M x 64N, BK=64, grid 1024 (4 blocks/CU). XCD remap: per-XCD working set = 8 mb-slices
// x 128 KB bf16 A + 2 MB W = 3 MB -> FITS the 4 MB XCD-L2 (fp32 dual-split was 6 MB and
// thrashed to IF$ at ~1.1 TB/s). Double-buffered LDS, one barrier/iter, loads pre-barrier.
__global__ __launch_bounds__(256, 4) void gemm_out(
    const unsigned short* __restrict__ Ab, const unsigned short* __restrict__ W,
    const float* __restrict__ bias, float* __restrict__ out){
    __shared__ unsigned short At[2][64*PIT];
    __shared__ unsigned short Wt[2][64*PIT];
    const int flat = blockIdx.x + (blockIdx.y << 4);  // [0,1024)
    const int xcd = flat & 7, idx = flat >> 3;        // idx [0,128)
    const int nb = idx & 15, mb = xcd*8 + (idx >> 4); // bijective: 8 XCD x 8 mb x 16 nb
    const int tid = threadIdx.x;
    const int wave = tid >> 6, lane = tid & 63, il = lane & 15, quad = lane >> 4;
    const int wm = wave & 1, wn = wave >> 1;
    const int mbase = mb*64, nbase = nb*64;
    const int srow = tid >> 2, scol = (tid & 3)*16;   // each thread: 1 row, 16 bf16 (2xuint4)

    f32x4 acc[2][2];
#pragma unroll
    for (int i = 0; i < 2; i++)
#pragma unroll
        for (int j = 0; j < 2; j++) acc[i][j] = (f32x4){0.f,0.f,0.f,0.f};

    const size_t aoff = (size_t)(mbase + srow)*EMB + scol;
    const size_t woff = (size_t)(nbase + srow)*EMB + scol;
    uint4 ap[2], wp[2];
    ap[0] = *(const uint4*)(Ab + aoff);
    ap[1] = *(const uint4*)(Ab + aoff + 8);
    wp[0] = *(const uint4*)(W + woff);
    wp[1] = *(const uint4*)(W + woff + 8);

    int c = 0;
    for (int kb = 0; kb < EMB; kb += 64){
        *(uint4*)&At[c][srow*PIT + scol]     = ap[0];
        *(uint4*)&At[c][srow*PIT + scol + 8] = ap[1];
        *(uint4*)&Wt[c][srow*PIT + scol]     = wp[0];
        *(uint4*)&Wt[c][srow*PIT + scol + 8] = wp[1];
        if (kb + 64 < EMB){
            ap[0] = *(const uint4*)(Ab + aoff + kb + 64);
            ap[1] = *(const uint4*)(Ab + aoff + kb + 64 + 8);
            wp[0] = *(const uint4*)(W + woff + kb + 64);
            wp[1] = *(const uint4*)(W + woff + kb + 64 + 8);
        }
        __syncthreads();
#pragma unroll
        for (int ks = 0; ks < 2; ks++){
            bf16x8 Af[2], Wf[2];
#pragma unroll
            for (int mt = 0; mt < 2; mt++)
                Af[mt] = *(const bf16x8*)(&At[c][(wm*32 + mt*16 + il)*PIT + ks*32 + quad*8]);
#pragma unroll
            for (int nt = 0; nt < 2; nt++)
                Wf[nt] = *(const bf16x8*)(&Wt[c][(wn*32 + nt*16 + il)*PIT + ks*32 + quad*8]);
#pragma unroll
            for (int mt = 0; mt < 2; mt++)
#pragma unroll
                for (int nt = 0; nt < 2; nt++)
                    acc[mt][nt] = __builtin_amdgcn_mfma_f32_16x16x32_bf16(Af[mt], Wf[nt], acc[mt][nt], 0, 0, 0);
        }
        c ^= 1;
    }
    float bb[2];
#pragma unroll
    for (int nt = 0; nt < 2; nt++) bb[nt] = bias[nbase + wn*32 + nt*16 + il];
#pragma unroll
    for (int mt = 0; mt < 2; mt++)
#pragma unroll
        for (int r = 0; r < 4; r++){
            int row = mbase + wm*32 + mt*16 + quad*4 + r;
            float* dst = &out[(size_t)row*EMB + nbase + wn*32 + il];
#pragma unroll
            for (int nt = 0; nt < 2; nt++)
                dst[nt*16] = acc[mt][nt][r] + bb[nt];
        }
}

extern "C" void kernel_launch(void* const* d_in, const int* in_sizes, int n_in,
                              void* d_out, int out_size, void* d_ws, size_t ws_size,
                              hipStream_t stream){
    const float* values = (const float*)d_in[0];
    const float* keys   = (const float*)d_in[1];
    const float* query  = (const float*)d_in[2];
    const int*   mask   = (const int*)d_in[3];
    const float* W_fc   = (const float*)d_in[4];
    const float* b_fc   = (const float*)d_in[5];
    float* out = (float*)d_out;

    char* ws = (char*)d_ws;
    unsigned short* Qb  = (unsigned short*)(ws);                        // 8 MiB
    unsigned short* Kb  = (unsigned short*)(ws + (8ull  << 20));        // 8 MiB
    unsigned short* Vtb = (unsigned short*)(ws + (16ull << 20));        // 8 MiB
    unsigned short* Wb  = (unsigned short*)(ws + (24ull << 20));        // 2 MiB
    unsigned*       Mb  = (unsigned*)      (ws + (26ull << 20));        // 1 MiB (bit-packed mask)
    unsigned short* Ab  = (unsigned short*)(ws + (27ull << 20));        // 8 MiB normalized bf16 O

    prep_all  <<<7168, 256, 0, stream>>>(query, keys, values, mask, W_fc,
                                         Qb, Kb, Vtb, Wb, Mb);
    flash_attn<<<dim3(32, 16, 2), 256, 0, stream>>>(Qb, Kb, Vtb, Mb, Ab);
    gemm_out  <<<dim3(16, 64), 256, 0, stream>>>(Ab, Wb, b_fc, out);
}

// Round 7
// 255.666 us; speedup vs baseline: 1.0277x; 1.0277x over previous
//
#include <hip/hip_runtime.h>
#include <cmath>

#define S_LEN 2048
#define EMB   1024
#define NHEAD 16
#define DHEAD 64
#define PIT   72   // LDS pitch (ushorts): 144B = 16B-aligned, worst 2-way bank alias (free per m136)

typedef __attribute__((ext_vector_type(8))) short bf16x8;
typedef __attribute__((ext_vector_type(4))) short bf16x4;
typedef __attribute__((ext_vector_type(4))) float f32x4;

// v_mfma_f32_16x16x16_bf16 (gfx90a-lineage builtin; instruction present on gfx950).
// Unconditional call passes host pass via deferred diagnostics (proven on HW in rounds 5-6).
#define MFMA16(a,b,c) __builtin_amdgcn_mfma_f32_16x16x16bf16_1k(a,b,c,0,0,0)

__device__ __forceinline__ unsigned short f2bf(float f){
    union { float f; unsigned u; } v; v.f = f;
    unsigned r = v.u + 0x7fffu + ((v.u >> 16) & 1u);
    return (unsigned short)(r >> 16);
}

__device__ __forceinline__ unsigned pk2bf(float a, float b){
#if __has_builtin(__builtin_amdgcn_cvt_pk_bf16_f32)
    typedef __attribute__((ext_vector_type(2))) __bf16 bf2;
    bf2 r = __builtin_amdgcn_cvt_pk_bf16_f32(a, b);
    return *(unsigned*)&r;
#else
    return (unsigned)f2bf(a) | ((unsigned)f2bf(b) << 16);
#endif
}

__device__ __forceinline__ float fast_exp2(float x){
#if __has_builtin(__builtin_amdgcn_exp2f)
    return __builtin_amdgcn_exp2f(x);
#else
    return exp2f(x);
#endif
}

__device__ __forceinline__ float fast_rcp(float x){
#if __has_builtin(__builtin_amdgcn_rcpf)
    return __builtin_amdgcn_rcpf(x);
#else
    return 1.0f / x;
#endif
}

// ---------------- fused prep: range-dispatched over blockIdx.x ----------------
// [0,4096):     Q (prescaled exp2-domain) + K -> bf16 [N,H,S,D]
// [4096,5120):  V -> bf16 transposed [N,H,D,S]
// [5120,6144):  W -> bf16
// [6144,7168):  mask int32 -> 1 BIT per element, Mb[n][q][k/32] uint32 (1 MB, L2-resident)
__global__ void prep_all(const float* __restrict__ q, const float* __restrict__ k,
                         const float* __restrict__ v, const int* __restrict__ mask,
                         const float* __restrict__ W,
                         unsigned short* __restrict__ Qb, unsigned short* __restrict__ Kb,
                         unsigned short* __restrict__ Vt, unsigned short* __restrict__ Wb,
                         unsigned* __restrict__ Mb){
    __shared__ unsigned short tile[64*68];
    const int b = blockIdx.x, tid = threadIdx.x;
    if (b < 4096){
        const float SC = 0.045084220027780106f;   // log2(e)/32
        int base = (b*256 + tid) * 4;
        int e = base & (EMB - 1);
        int s = (base >> 10) & (S_LEN - 1);
        int n = base >> 21;
        int h = e >> 6, d = e & 63;
        int dst = ((n*NHEAD + h)*S_LEN + s)*DHEAD + d;
        float4 qv = *(const float4*)(q + base);
        float4 kv = *(const float4*)(k + base);
        uint2 qp, kp;
        qp.x = pk2bf(qv.x*SC, qv.y*SC);
        qp.y = pk2bf(qv.z*SC, qv.w*SC);
        kp.x = pk2bf(kv.x, kv.y);
        kp.y = pk2bf(kv.z, kv.w);
        *(uint2*)(Qb + dst) = qp;
        *(uint2*)(Kb + dst) = kp;
    } else if (b < 5120){
        int idx = b - 4096;
        int st = idx & 31, h = (idx >> 5) & 15, n = idx >> 9;
        int sbase = st * 64;
#pragma unroll
        for (int i = 0; i < 4; i++){
            int c = tid + i*256;
            int srow = c >> 4, c4 = (c & 15) * 4;
            float4 x = *(const float4*)(v + (n*S_LEN + sbase + srow)*EMB + h*DHEAD + c4);
            uint2 p;
            p.x = pk2bf(x.x, x.y);
            p.y = pk2bf(x.z, x.w);
            *(uint2*)&tile[srow*68 + c4] = p;
        }
        __syncthreads();
#pragma unroll
        for (int i = 0; i < 2; i++){
            int c = tid + i*256;
            int d = c >> 3, s8 = (c & 7) * 8;
            unsigned u0 = (unsigned)tile[(s8+0)*68 + d] | ((unsigned)tile[(s8+1)*68 + d] << 16);
            unsigned u1 = (unsigned)tile[(s8+2)*68 + d] | ((unsigned)tile[(s8+3)*68 + d] << 16);
            unsigned u2 = (unsigned)tile[(s8+4)*68 + d] | ((unsigned)tile[(s8+5)*68 + d] << 16);
            unsigned u3 = (unsigned)tile[(s8+6)*68 + d] | ((unsigned)tile[(s8+7)*68 + d] << 16);
            uint4 pk; pk.x = u0; pk.y = u1; pk.z = u2; pk.w = u3;
            *(uint4*)(Vt + ((n*NHEAD + h)*DHEAD + d)*S_LEN + sbase + s8) = pk;
        }
    } else if (b < 6144){
        int base = ((b - 5120)*256 + tid) * 4;
        float4 x = *(const float4*)(W + base);
        uint2 p;
        p.x = pk2bf(x.x, x.y);
        p.y = pk2bf(x.z, x.w);
        *(uint2*)(Wb + base) = p;
    } else {
        int u = (b - 6144)*256 + tid;                 // [0, 262144)
        const int4* m4 = (const int4*)mask + (size_t)u*8;
        unsigned w = 0;
#pragma unroll
        for (int i = 0; i < 8; i++){
            int4 m = m4[i];
            unsigned nib = (m.x ? 1u : 0u) | (m.y ? 2u : 0u) | (m.z ? 4u : 0u) | (m.w ? 8u : 0u);
            w |= nib << (i*4);
        }
        Mb[u] = w;
    }
}

// ---------------- flash attention: 8-wave blocks, 256 q-rows, FULL K, normalize in-kernel --
// Round-6 regression root-caused: 64-row blocks doubled total K/V staging (1024 blocks x full
// 2048 K). This version amortizes: 256 blocks (1/CU) x 8 waves x 32 q-rows/wave. Per staged
// 64-row K/V tile the block does 4x round-6's MFMA work; total staging instrs and global K/V
// reads drop 4x (each thread stages ONE uint4 of K + ONE of V per iter). Double-buffered LDS,
// one barrier/iter; P never touches LDS (QK^T C-layout == K=16 A-frag layout); normalize
// in-register at epilogue and store bf16 O (accL[r] lives in the same lane as acc[dt][r]).
__global__ __launch_bounds__(512, 2) void flash_attn(
    const unsigned short* __restrict__ Qb, const unsigned short* __restrict__ Kb,
    const unsigned short* __restrict__ Vt, const unsigned* __restrict__ Mb,
    unsigned short* __restrict__ Ab){
    __shared__ unsigned short Kt[2][64*PIT];
    __shared__ unsigned short Vl[2][64*PIT];
    __shared__ uint2 mlut[16];

    const int tid = threadIdx.x;
    if (tid < 16){
        uint2 e;
        e.x = ((tid & 1) ? 0xFFFFu : 0u) | ((tid & 2) ? 0xFFFF0000u : 0u);
        e.y = ((tid & 4) ? 0xFFFFu : 0u) | ((tid & 8) ? 0xFFFF0000u : 0u);
        mlut[tid] = e;
    }

    // XCD-aware remap: flat [0,256); each XCD owns 4 (n,h) slices x 8 qt-blocks.
    const int flat = blockIdx.x + (blockIdx.y << 3);  // grid (8, 32)
    const int xcd = flat & 7, idx = flat >> 3;        // idx [0,32)
    const int qt = idx & 7;
    const int sl = xcd + ((idx >> 3) << 3);           // [0,32)
    const int h = sl & 15, n = sl >> 4;

    const int wave = tid >> 6, lane = tid & 63, il = lane & 15, quad = lane >> 4;
    const int qbase = qt*256 + wave*32;

    const unsigned short* Qh = Qb + (n*NHEAD + h)*S_LEN*DHEAD;
    const unsigned short* Kh = Kb + (n*NHEAD + h)*S_LEN*DHEAD;
    const unsigned short* Vh = Vt + (n*NHEAD + h)*DHEAD*S_LEN;
    const unsigned* mr0 = Mb + (size_t)(n*S_LEN + qbase + il)*(S_LEN/32);
    const unsigned* mr1 = mr0 + 16*(S_LEN/32);

    // staging: 512 threads cover the whole 64-row tile in one uint4 each (K and V)
    const int srow = tid >> 3, scol = (tid & 7)*8;

    bf16x8 Qf[2][2];   // B-operand frags: n=il -> q row, k = quad*8+j -> d
#pragma unroll
    for (int rt = 0; rt < 2; rt++)
#pragma unroll
        for (int ks = 0; ks < 2; ks++)
            Qf[rt][ks] = *(const bf16x8*)(Qh + (qbase + rt*16 + il)*DHEAD + ks*32 + quad*8);

    f32x4 acc[2][4], accL[2];
#pragma unroll
    for (int rt = 0; rt < 2; rt++){
        accL[rt] = (f32x4){0.f,0.f,0.f,0.f};
#pragma unroll
        for (int j = 0; j < 4; j++) acc[rt][j] = (f32x4){0.f,0.f,0.f,0.f};
    }
    const short onev = 0x3F80;   // bf16 1.0
    const bf16x4 ones4 = {onev,onev,onev,onev};
    const int q4 = quad*4;

    // prefetch tile 0
    uint4 kpre = *(const uint4*)(Kh + srow*DHEAD + scol);
    uint4 vpre = *(const uint4*)(Vh + srow*S_LEN + scol);

    int c = 0;
    for (int kb = 0; kb < S_LEN; kb += 64){
        // drain prefetch regs into LDS buf c (laggards still read buf c^1: disjoint)
        *(uint4*)&Kt[c][srow*PIT + scol] = kpre;
        *(uint4*)&Vl[c][srow*PIT + scol] = vpre;
        // issue next tile's loads BEFORE the barrier: covered by the full compute phase
        if (kb + 64 < S_LEN){
            kpre = *(const uint4*)(Kh + (kb + 64 + srow)*DHEAD + scol);
            vpre = *(const uint4*)(Vh + srow*S_LEN + kb + 64 + scol);
        }
        // mask bits for this 64-wide k-tile (L2-resident, independent of LDS)
        uint2 w0 = *(const uint2*)(mr0 + (kb >> 5));
        uint2 w1 = *(const uint2*)(mr1 + (kb >> 5));
        __syncthreads();

        // E^T = K.Q^T : A = K rows, B = Q rows. C: col=il -> q, row=quad*4+r -> k
        f32x4 e[2][4];
#pragma unroll
        for (int t = 0; t < 4; t++){
            bf16x8 kf0 = *(const bf16x8*)(&Kt[c][(t*16 + il)*PIT + quad*8]);
            bf16x8 kf1 = *(const bf16x8*)(&Kt[c][(t*16 + il)*PIT + 32 + quad*8]);
#pragma unroll
            for (int rt = 0; rt < 2; rt++){
                f32x4 z = (f32x4){0.f,0.f,0.f,0.f};
                z        = __builtin_amdgcn_mfma_f32_16x16x32_bf16(kf0, Qf[rt][0], z, 0, 0, 0);
                e[rt][t] = __builtin_amdgcn_mfma_f32_16x16x32_bf16(kf1, Qf[rt][1], z, 0, 0, 0);
            }
        }
        // p = exp2(e); mask as AND on packed bf16 pairs. pw[rt][t] is a ready K=16 A-frag.
        unsigned pw[2][4][2];
#pragma unroll
        for (int rt = 0; rt < 2; rt++){
            const uint2 w = rt ? w1 : w0;
            unsigned s0 = w.x >> q4, s1 = w.y >> q4;
            unsigned s0h = s0 >> 16, s1h = s1 >> 16;
#pragma unroll
            for (int t = 0; t < 4; t++){
                unsigned s = (t == 0) ? s0 : (t == 1) ? s0h : (t == 2) ? s1 : s1h;
                uint2 mw = mlut[s & 0xFu];
                float p0 = fast_exp2(e[rt][t][0]);
                float p1 = fast_exp2(e[rt][t][1]);
                float p2 = fast_exp2(e[rt][t][2]);
                float p3 = fast_exp2(e[rt][t][3]);
                pw[rt][t][0] = pk2bf(p0, p1) & mw.x;
                pw[rt][t][1] = pk2bf(p2, p3) & mw.y;
            }
        }
        // PV: O += P.V ; l += P.1 — K=16 MFMAs, P straight from registers
#pragma unroll
        for (int t = 0; t < 4; t++){
            bf16x4 Pa[2];
#pragma unroll
            for (int rt = 0; rt < 2; rt++){
                uint2 u; u.x = pw[rt][t][0]; u.y = pw[rt][t][1];
                Pa[rt] = *(bf16x4*)&u;
                accL[rt] = MFMA16(Pa[rt], ones4, accL[rt]);
            }
#pragma unroll
            for (int dt = 0; dt < 4; dt++){
                bf16x4 Vf = *(const bf16x4*)(&Vl[c][(dt*16 + il)*PIT + t*16 + quad*4]);
#pragma unroll
                for (int rt = 0; rt < 2; rt++)
                    acc[rt][dt] = MFMA16(Pa[rt], Vf, acc[rt][dt]);
            }
        }
        c ^= 1;
    }

    // epilogue: normalize in-register (accL full row sums) and store bf16 O rows
#pragma unroll
    for (int rt = 0; rt < 2; rt++)
#pragma unroll
        for (int r = 0; r < 4; r++){
            float inv = fast_rcp(accL[rt][r]);
            size_t row = (size_t)(n*S_LEN + qbase + rt*16 + quad*4 + r);
            unsigned short* dst = Ab + row*EMB + h*DHEAD + il;
#pragma unroll
            for (int dt = 0; dt < 4; dt++)
                dst[dt*16] = f2bf(acc[rt][dt][r]*inv);
        }
}

// ---------------- output GEMM: out = Ab.W^T + b (A already normalized bf16) --------------
// 64M x 64N, BK=64, grid 1024 (4 blocks/CU). XCD remap: per-XCD working set = 8 mb-slices
// x 128 KB bf16 A + 2 MB W = 3 MB -> fits the 4 MB XCD-L2. Double-buffered LDS, one
// barrier/iter, loads issued pre-barrier.
__global__ __launch_bounds__(256, 4) void gemm_out(
    const unsigned short* __restrict__ Ab, const unsigned short* __restrict__ W,
    const float* __restrict__ bias, float* __restrict__ out){
    __shared__ unsigned short At[2][64*PIT];
    __shared__ unsigned short Wt[2][64*PIT];
    const int flat = blockIdx.x + (blockIdx.y << 4);  // [0,1024)
    const int xcd = flat & 7, idx = flat >> 3;        // idx [0,128)
    const int nb = idx & 15, mb = xcd*8 + (idx >> 4); // bijective: 8 XCD x 8 mb x 16 nb
    const int tid = threadIdx.x;
    const int wave = tid >> 6, lane = tid & 63, il = lane & 15, quad = lane >> 4;
    const int wm = wave & 1, wn = wave >> 1;
    const int mbase = mb*64, nbase = nb*64;
    const int srow = tid >> 2, scol = (tid & 3)*16;   // each thread: 1 row, 16 bf16 (2xuint4)

    f32x4 acc[2][2];
#pragma unroll
    for (int i = 0; i < 2; i++)
#pragma unroll
        for (int j = 0; j < 2; j++) acc[i][j] = (f32x4){0.f,0.f,0.f,0.f};

    const size_t aoff = (size_t)(mbase + srow)*EMB + scol;
    const size_t woff = (size_t)(nbase + srow)*EMB + scol;
    uint4 ap[2], wp[2];
    ap[0] = *(const uint4*)(Ab + aoff);
    ap[1] = *(const uint4*)(Ab + aoff + 8);
    wp[0] = *(const uint4*)(W + woff);
    wp[1] = *(const uint4*)(W + woff + 8);

    int c = 0;
    for (int kb = 0; kb < EMB; kb += 64){
        *(uint4*)&At[c][srow*PIT + scol]     = ap[0];
        *(uint4*)&At[c][srow*PIT + scol + 8] = ap[1];
        *(uint4*)&Wt[c][srow*PIT + scol]     = wp[0];
        *(uint4*)&Wt[c][srow*PIT + scol + 8] = wp[1];
        if (kb + 64 < EMB){
            ap[0] = *(const uint4*)(Ab + aoff + kb + 64);
            ap[1] = *(const uint4*)(Ab + aoff + kb + 64 + 8);
            wp[0] = *(const uint4*)(W + woff + kb + 64);
            wp[1] = *(const uint4*)(W + woff + kb + 64 + 8);
        }
        __syncthreads();
#pragma unroll
        for (int ks = 0; ks < 2; ks++){
            bf16x8 Af[2], Wf[2];
#pragma unroll
            for (int mt = 0; mt < 2; mt++)
                Af[mt] = *(const bf16x8*)(&At[c][(wm*32 + mt*16 + il)*PIT + ks*32 + quad*8]);
#pragma unroll
            for (int nt = 0; nt < 2; nt++)
                Wf[nt] = *(const bf16x8*)(&Wt[c][(wn*32 + nt*16 + il)*PIT + ks*32 + quad*8]);
#pragma unroll
            for (int mt = 0; mt < 2; mt++)
#pragma unroll
                for (int nt = 0; nt < 2; nt++)
                    acc[mt][nt] = __builtin_amdgcn_mfma_f32_16x16x32_bf16(Af[mt], Wf[nt], acc[mt][nt], 0, 0, 0);
        }
        c ^= 1;
    }
    float bb[2];
#pragma unroll
    for (int nt = 0; nt < 2; nt++) bb[nt] = bias[nbase + wn*32 + nt*16 + il];
#pragma unroll
    for (int mt = 0; mt < 2; mt++)
#pragma unroll
        for (int r = 0; r < 4; r++){
            int row = mbase + wm*32 + mt*16 + quad*4 + r;
            float* dst = &out[(size_t)row*EMB + nbase + wn*32 + il];
#pragma unroll
            for (int nt = 0; nt < 2; nt++)
                dst[nt*16] = acc[mt][nt][r] + bb[nt];
        }
}

extern "C" void kernel_launch(void* const* d_in, const int* in_sizes, int n_in,
                              void* d_out, int out_size, void* d_ws, size_t ws_size,
                              hipStream_t stream){
    const float* values = (const float*)d_in[0];
    const float* keys   = (const float*)d_in[1];
    const float* query  = (const float*)d_in[2];
    const int*   mask   = (const int*)d_in[3];
    const float* W_fc   = (const float*)d_in[4];
    const float* b_fc   = (const float*)d_in[5];
    float* out = (float*)d_out;

    char* ws = (char*)d_ws;
    unsigned short* Qb  = (unsigned short*)(ws);                        // 8 MiB
    unsigned short* Kb  = (unsigned short*)(ws + (8ull  << 20));        // 8 MiB
    unsigned short* Vtb = (unsigned short*)(ws + (16ull << 20));        // 8 MiB
    unsigned short* Wb  = (unsigned short*)(ws + (24ull << 20));        // 2 MiB
    unsigned*       Mb  = (unsigned*)      (ws + (26ull << 20));        // 1 MiB (bit-packed mask)
    unsigned short* Ab  = (unsigned short*)(ws + (27ull << 20));        // 8 MiB normalized bf16 O

    prep_all  <<<7168, 256, 0, stream>>>(query, keys, values, mask, W_fc,
                                         Qb, Kb, Vtb, Wb, Mb);
    flash_attn<<<dim3(8, 32), 512, 0, stream>>>(Qb, Kb, Vtb, Mb, Ab);
    gemm_out  <<<dim3(16, 64), 256, 0, stream>>>(Ab, Wb, b_fc, out);
}

// Round 8
// 246.587 us; speedup vs baseline: 1.0656x; 1.0368x over previous
//
#include <hip/hip_runtime.h>
#include <cmath>

#define S_LEN 2048
#define EMB   1024
#define NHEAD 16
#define DHEAD 64
#define PIT   72   // LDS pitch (ushorts): 144B = 16B-aligned, worst 2-way bank alias (free per m136)

typedef __attribute__((ext_vector_type(8))) short bf16x8;
typedef __attribute__((ext_vector_type(4))) short bf16x4;
typedef __attribute__((ext_vector_type(4))) float f32x4;

// v_mfma_f32_16x16x16_bf16 (gfx90a-lineage builtin; instruction present on gfx950).
// Unconditional call passes host pass via deferred diagnostics (proven on HW in rounds 5-7).
#define MFMA16(a,b,c) __builtin_amdgcn_mfma_f32_16x16x16bf16_1k(a,b,c,0,0,0)

__device__ __forceinline__ unsigned short f2bf(float f){
    union { float f; unsigned u; } v; v.f = f;
    unsigned r = v.u + 0x7fffu + ((v.u >> 16) & 1u);
    return (unsigned short)(r >> 16);
}

__device__ __forceinline__ unsigned pk2bf(float a, float b){
#if __has_builtin(__builtin_amdgcn_cvt_pk_bf16_f32)
    typedef __attribute__((ext_vector_type(2))) __bf16 bf2;
    bf2 r = __builtin_amdgcn_cvt_pk_bf16_f32(a, b);
    return *(unsigned*)&r;
#else
    return (unsigned)f2bf(a) | ((unsigned)f2bf(b) << 16);
#endif
}

__device__ __forceinline__ float fast_exp2(float x){
#if __has_builtin(__builtin_amdgcn_exp2f)
    return __builtin_amdgcn_exp2f(x);
#else
    return exp2f(x);
#endif
}

__device__ __forceinline__ float fast_rcp(float x){
#if __has_builtin(__builtin_amdgcn_rcpf)
    return __builtin_amdgcn_rcpf(x);
#else
    return 1.0f / x;
#endif
}

// ---------------- fused prep: range-dispatched over blockIdx.x ----------------
// [0,4096):     Q (prescaled exp2-domain) + K -> bf16 [N,H,S,D]
// [4096,5120):  V -> bf16 transposed [N,H,D,S]
// [5120,6144):  W -> bf16
// [6144,7168):  mask int32 -> 1 BIT per element, Mb[n][q][k/32] uint32 (1 MB, L2-resident)
__global__ void prep_all(const float* __restrict__ q, const float* __restrict__ k,
                         const float* __restrict__ v, const int* __restrict__ mask,
                         const float* __restrict__ W,
                         unsigned short* __restrict__ Qb, unsigned short* __restrict__ Kb,
                         unsigned short* __restrict__ Vt, unsigned short* __restrict__ Wb,
                         unsigned* __restrict__ Mb){
    __shared__ unsigned short tile[64*68];
    const int b = blockIdx.x, tid = threadIdx.x;
    if (b < 4096){
        const float SC = 0.045084220027780106f;   // log2(e)/32
        int base = (b*256 + tid) * 4;
        int e = base & (EMB - 1);
        int s = (base >> 10) & (S_LEN - 1);
        int n = base >> 21;
        int h = e >> 6, d = e & 63;
        int dst = ((n*NHEAD + h)*S_LEN + s)*DHEAD + d;
        float4 qv = *(const float4*)(q + base);
        float4 kv = *(const float4*)(k + base);
        uint2 qp, kp;
        qp.x = pk2bf(qv.x*SC, qv.y*SC);
        qp.y = pk2bf(qv.z*SC, qv.w*SC);
        kp.x = pk2bf(kv.x, kv.y);
        kp.y = pk2bf(kv.z, kv.w);
        *(uint2*)(Qb + dst) = qp;
        *(uint2*)(Kb + dst) = kp;
    } else if (b < 5120){
        int idx = b - 4096;
        int st = idx & 31, h = (idx >> 5) & 15, n = idx >> 9;
        int sbase = st * 64;
#pragma unroll
        for (int i = 0; i < 4; i++){
            int c = tid + i*256;
            int srow = c >> 4, c4 = (c & 15) * 4;
            float4 x = *(const float4*)(v + (n*S_LEN + sbase + srow)*EMB + h*DHEAD + c4);
            uint2 p;
            p.x = pk2bf(x.x, x.y);
            p.y = pk2bf(x.z, x.w);
            *(uint2*)&tile[srow*68 + c4] = p;
        }
        __syncthreads();
#pragma unroll
        for (int i = 0; i < 2; i++){
            int c = tid + i*256;
            int d = c >> 3, s8 = (c & 7) * 8;
            unsigned u0 = (unsigned)tile[(s8+0)*68 + d] | ((unsigned)tile[(s8+1)*68 + d] << 16);
            unsigned u1 = (unsigned)tile[(s8+2)*68 + d] | ((unsigned)tile[(s8+3)*68 + d] << 16);
            unsigned u2 = (unsigned)tile[(s8+4)*68 + d] | ((unsigned)tile[(s8+5)*68 + d] << 16);
            unsigned u3 = (unsigned)tile[(s8+6)*68 + d] | ((unsigned)tile[(s8+7)*68 + d] << 16);
            uint4 pk; pk.x = u0; pk.y = u1; pk.z = u2; pk.w = u3;
            *(uint4*)(Vt + ((n*NHEAD + h)*DHEAD + d)*S_LEN + sbase + s8) = pk;
        }
    } else if (b < 6144){
        int base = ((b - 5120)*256 + tid) * 4;
        float4 x = *(const float4*)(W + base);
        uint2 p;
        p.x = pk2bf(x.x, x.y);
        p.y = pk2bf(x.z, x.w);
        *(uint2*)(Wb + base) = p;
    } else {
        int u = (b - 6144)*256 + tid;                 // [0, 262144)
        const int4* m4 = (const int4*)mask + (size_t)u*8;
        unsigned w = 0;
#pragma unroll
        for (int i = 0; i < 8; i++){
            int4 m = m4[i];
            unsigned nib = (m.x ? 1u : 0u) | (m.y ? 2u : 0u) | (m.z ? 4u : 0u) | (m.w ? 8u : 0u);
            w |= nib << (i*4);
        }
        Mb[u] = w;
    }
}

// ---------------- flash attention: 8-wave blocks, 256 q-rows, FULL K, normalize in-kernel --
// ROUND-8 FIX: prefetch loads (and mask loads) issue AFTER __syncthreads, not before.
// __syncthreads emits s_waitcnt vmcnt(0) (barrier drain) — loads issued pre-barrier were
// drained with ZERO latency cover every iteration (the 75-77 µs invariance of rounds 5-7).
// Post-barrier loads are consumed at the NEXT iter's ds_write (vmcnt, no barrier between),
// so the in-flight window = the full QK+softmax+PV compute phase.
__global__ __launch_bounds__(512, 2) void flash_attn(
    const unsigned short* __restrict__ Qb, const unsigned short* __restrict__ Kb,
    const unsigned short* __restrict__ Vt, const unsigned* __restrict__ Mb,
    unsigned short* __restrict__ Ab){
    __shared__ unsigned short Kt[2][64*PIT];
    __shared__ unsigned short Vl[2][64*PIT];
    __shared__ uint2 mlut[16];

    const int tid = threadIdx.x;
    if (tid < 16){
        uint2 e;
        e.x = ((tid & 1) ? 0xFFFFu : 0u) | ((tid & 2) ? 0xFFFF0000u : 0u);
        e.y = ((tid & 4) ? 0xFFFFu : 0u) | ((tid & 8) ? 0xFFFF0000u : 0u);
        mlut[tid] = e;
    }

    // XCD-aware remap: flat [0,256); each XCD owns 4 (n,h) slices x 8 qt-blocks.
    const int flat = blockIdx.x + (blockIdx.y << 3);  // grid (8, 32)
    const int xcd = flat & 7, idx = flat >> 3;        // idx [0,32)
    const int qt = idx & 7;
    const int sl = xcd + ((idx >> 3) << 3);           // [0,32)
    const int h = sl & 15, n = sl >> 4;

    const int wave = tid >> 6, lane = tid & 63, il = lane & 15, quad = lane >> 4;
    const int qbase = qt*256 + wave*32;

    const unsigned short* Qh = Qb + (n*NHEAD + h)*S_LEN*DHEAD;
    const unsigned short* Kh = Kb + (n*NHEAD + h)*S_LEN*DHEAD;
    const unsigned short* Vh = Vt + (n*NHEAD + h)*DHEAD*S_LEN;
    const unsigned* mr0 = Mb + (size_t)(n*S_LEN + qbase + il)*(S_LEN/32);
    const unsigned* mr1 = mr0 + 16*(S_LEN/32);

    // staging: 512 threads cover the whole 64-row tile in one uint4 each (K and V)
    const int srow = tid >> 3, scol = (tid & 7)*8;

    bf16x8 Qf[2][2];   // B-operand frags: n=il -> q row, k = quad*8+j -> d
#pragma unroll
    for (int rt = 0; rt < 2; rt++)
#pragma unroll
        for (int ks = 0; ks < 2; ks++)
            Qf[rt][ks] = *(const bf16x8*)(Qh + (qbase + rt*16 + il)*DHEAD + ks*32 + quad*8);

    f32x4 acc[2][4], accL[2];
#pragma unroll
    for (int rt = 0; rt < 2; rt++){
        accL[rt] = (f32x4){0.f,0.f,0.f,0.f};
#pragma unroll
        for (int j = 0; j < 4; j++) acc[rt][j] = (f32x4){0.f,0.f,0.f,0.f};
    }
    const short onev = 0x3F80;   // bf16 1.0
    const bf16x4 ones4 = {onev,onev,onev,onev};
    const int q4 = quad*4;

    // prefetch tile 0
    uint4 kpre = *(const uint4*)(Kh + srow*DHEAD + scol);
    uint4 vpre = *(const uint4*)(Vh + srow*S_LEN + scol);

    int c = 0;
    for (int kb = 0; kb < S_LEN; kb += 64){
        // drain prefetch regs into LDS buf c (vmcnt wait here had the whole PREVIOUS
        // compute phase as cover). Laggard waves still read buf c^1: disjoint.
        *(uint4*)&Kt[c][srow*PIT + scol] = kpre;
        *(uint4*)&Vl[c][srow*PIT + scol] = vpre;
        __syncthreads();   // nothing in flight here -> barrier drain costs nothing
        // issue next tile's loads AFTER the barrier: in flight across this whole
        // compute phase, consumed at next iter's ds_write (no barrier in between).
        if (kb + 64 < S_LEN){
            kpre = *(const uint4*)(Kh + (kb + 64 + srow)*DHEAD + scol);
            vpre = *(const uint4*)(Vh + srow*S_LEN + kb + 64 + scol);
        }
        // mask bits for this 64-wide k-tile (L2-resident; consumed in the P phase below)
        uint2 w0 = *(const uint2*)(mr0 + (kb >> 5));
        uint2 w1 = *(const uint2*)(mr1 + (kb >> 5));

        // E^T = K.Q^T : A = K rows, B = Q rows. C: col=il -> q, row=quad*4+r -> k
        f32x4 e[2][4];
#pragma unroll
        for (int t = 0; t < 4; t++){
            bf16x8 kf0 = *(const bf16x8*)(&Kt[c][(t*16 + il)*PIT + quad*8]);
            bf16x8 kf1 = *(const bf16x8*)(&Kt[c][(t*16 + il)*PIT + 32 + quad*8]);
#pragma unroll
            for (int rt = 0; rt < 2; rt++){
                f32x4 z = (f32x4){0.f,0.f,0.f,0.f};
                z        = __builtin_amdgcn_mfma_f32_16x16x32_bf16(kf0, Qf[rt][0], z, 0, 0, 0);
                e[rt][t] = __builtin_amdgcn_mfma_f32_16x16x32_bf16(kf1, Qf[rt][1], z, 0, 0, 0);
            }
        }
        // p = exp2(e); mask as AND on packed bf16 pairs. pw[rt][t] is a ready K=16 A-frag.
        unsigned pw[2][4][2];
#pragma unroll
        for (int rt = 0; rt < 2; rt++){
            const uint2 w = rt ? w1 : w0;
            unsigned s0 = w.x >> q4, s1 = w.y >> q4;
            unsigned s0h = s0 >> 16, s1h = s1 >> 16;
#pragma unroll
            for (int t = 0; t < 4; t++){
                unsigned s = (t == 0) ? s0 : (t == 1) ? s0h : (t == 2) ? s1 : s1h;
                uint2 mw = mlut[s & 0xFu];
                float p0 = fast_exp2(e[rt][t][0]);
                float p1 = fast_exp2(e[rt][t][1]);
                float p2 = fast_exp2(e[rt][t][2]);
                float p3 = fast_exp2(e[rt][t][3]);
                pw[rt][t][0] = pk2bf(p0, p1) & mw.x;
                pw[rt][t][1] = pk2bf(p2, p3) & mw.y;
            }
        }
        // PV: O += P.V ; l += P.1 — K=16 MFMAs, P straight from registers
#pragma unroll
        for (int t = 0; t < 4; t++){
            bf16x4 Pa[2];
#pragma unroll
            for (int rt = 0; rt < 2; rt++){
                uint2 u; u.x = pw[rt][t][0]; u.y = pw[rt][t][1];
                Pa[rt] = *(bf16x4*)&u;
                accL[rt] = MFMA16(Pa[rt], ones4, accL[rt]);
            }
#pragma unroll
            for (int dt = 0; dt < 4; dt++){
                bf16x4 Vf = *(const bf16x4*)(&Vl[c][(dt*16 + il)*PIT + t*16 + quad*4]);
#pragma unroll
                for (int rt = 0; rt < 2; rt++)
                    acc[rt][dt] = MFMA16(Pa[rt], Vf, acc[rt][dt]);
            }
        }
        c ^= 1;
    }

    // epilogue: normalize in-register (accL full row sums) and store bf16 O rows
#pragma unroll
    for (int rt = 0; rt < 2; rt++)
#pragma unroll
        for (int r = 0; r < 4; r++){
            float inv = fast_rcp(accL[rt][r]);
            size_t row = (size_t)(n*S_LEN + qbase + rt*16 + quad*4 + r);
            unsigned short* dst = Ab + row*EMB + h*DHEAD + il;
#pragma unroll
            for (int dt = 0; dt < 4; dt++)
                dst[dt*16] = f2bf(acc[rt][dt][r]*inv);
        }
}

// ---------------- output GEMM: out = Ab.W^T + b — DIRECT-REG, no LDS, no barriers --------
// Within a block each A byte is used ONCE and each W byte TWICE: LDS staging has zero reuse
// value and only added the ds_write -> vmcnt -> barrier-drain chain (the 75 µs invariance).
// MFMA A/B frags are loaded per-lane straight from global: per instruction a wave reads
// 16 rows x 64 contiguous bytes (full-line coalesced), L2-resident per XCD via the remap.
// Fully unrolled, barrier-free: the scheduler pipelines loads iterations ahead.
__global__ __launch_bounds__(256, 4) void gemm_out(
    const unsigned short* __restrict__ Ab, const unsigned short* __restrict__ W,
    const float* __restrict__ bias, float* __restrict__ out){
    const int flat = blockIdx.x + (blockIdx.y << 4);  // [0,1024)
    const int xcd = flat & 7, idx = flat >> 3;        // idx [0,128)
    const int nb = idx & 15, mb = xcd*8 + (idx >> 4); // bijective: 8 XCD x 8 mb x 16 nb
    const int tid = threadIdx.x;
    const int wave = tid >> 6, lane = tid & 63, il = lane & 15, quad = lane >> 4;
    const int wm = wave & 1, wn = wave >> 1;
    const int mbase = mb*64, nbase = nb*64;

    f32x4 acc[2][2];
#pragma unroll
    for (int i = 0; i < 2; i++)
#pragma unroll
        for (int j = 0; j < 2; j++) acc[i][j] = (f32x4){0.f,0.f,0.f,0.f};

    const unsigned short* A0 = Ab + (size_t)(mbase + wm*32 + il)*EMB + quad*8;
    const unsigned short* W0 = W  + (size_t)(nbase + wn*32 + il)*EMB + quad*8;

#pragma unroll
    for (int kb = 0; kb < EMB; kb += 64){
        bf16x8 Af[2][2], Wf[2][2];
#pragma unroll
        for (int mt = 0; mt < 2; mt++)
#pragma unroll
            for (int ks = 0; ks < 2; ks++)
                Af[mt][ks] = *(const bf16x8*)(A0 + (size_t)mt*16*EMB + kb + ks*32);
#pragma unroll
        for (int nt = 0; nt < 2; nt++)
#pragma unroll
            for (int ks = 0; ks < 2; ks++)
                Wf[nt][ks] = *(const bf16x8*)(W0 + (size_t)nt*16*EMB + kb + ks*32);
#pragma unroll
        for (int ks = 0; ks < 2; ks++)
#pragma unroll
            for (int mt = 0; mt < 2; mt++)
#pragma unroll
                for (int nt = 0; nt < 2; nt++)
                    acc[mt][nt] = __builtin_amdgcn_mfma_f32_16x16x32_bf16(Af[mt][ks], Wf[nt][ks], acc[mt][nt], 0, 0, 0);
    }

    float bb[2];
#pragma unroll
    for (int nt = 0; nt < 2; nt++) bb[nt] = bias[nbase + wn*32 + nt*16 + il];
#pragma unroll
    for (int mt = 0; mt < 2; mt++)
#pragma unroll
        for (int r = 0; r < 4; r++){
            int row = mbase + wm*32 + mt*16 + quad*4 + r;
            float* dst = &out[(size_t)row*EMB + nbase + wn*32 + il];
#pragma unroll
            for (int nt = 0; nt < 2; nt++)
                dst[nt*16] = acc[mt][nt][r] + bb[nt];
        }
}

extern "C" void kernel_launch(void* const* d_in, const int* in_sizes, int n_in,
                              void* d_out, int out_size, void* d_ws, size_t ws_size,
                              hipStream_t stream){
    const float* values = (const float*)d_in[0];
    const float* keys   = (const float*)d_in[1];
    const float* query  = (const float*)d_in[2];
    const int*   mask   = (const int*)d_in[3];
    const float* W_fc   = (const float*)d_in[4];
    const float* b_fc   = (const float*)d_in[5];
    float* out = (float*)d_out;

    char* ws = (char*)d_ws;
    unsigned short* Qb  = (unsigned short*)(ws);                        // 8 MiB
    unsigned short* Kb  = (unsigned short*)(ws + (8ull  << 20));        // 8 MiB
    unsigned short* Vtb = (unsigned short*)(ws + (16ull << 20));        // 8 MiB
    unsigned short* Wb  = (unsigned short*)(ws + (24ull << 20));        // 2 MiB
    unsigned*       Mb  = (unsigned*)      (ws + (26ull << 20));        // 1 MiB (bit-packed mask)
    unsigned short* Ab  = (unsigned short*)(ws + (27ull << 20));        // 8 MiB normalized bf16 O

    prep_all  <<<7168, 256, 0, stream>>>(query, keys, values, mask, W_fc,
                                         Qb, Kb, Vtb, Wb, Mb);
    flash_attn<<<dim3(8, 32), 512, 0, stream>>>(Qb, Kb, Vtb, Mb, Ab);
    gemm_out  <<<dim3(16, 64), 256, 0, stream>>>(Ab, Wb, b_fc, out);
}

// Round 9
// 235.181 us; speedup vs baseline: 1.1172x; 1.0485x over previous
//
#include <hip/hip_runtime.h>
#include <cmath>

#define S_LEN 2048
#define EMB   1024
#define NHEAD 16
#define DHEAD 64
#define PIT   72   // ushort pitch for prep/gemm LDS tiles (144B)

typedef __attribute__((ext_vector_type(8)))  short bf16x8;
typedef __attribute__((ext_vector_type(4)))  short bf16x4;
typedef __attribute__((ext_vector_type(4)))  float f32x4;
typedef __attribute__((ext_vector_type(16))) float f32x16;

#define MFMA32(a,b,c) __builtin_amdgcn_mfma_f32_32x32x16_bf16(a,b,c,0,0,0)

__device__ __forceinline__ unsigned short f2bf(float f){
    union { float f; unsigned u; } v; v.f = f;
    unsigned r = v.u + 0x7fffu + ((v.u >> 16) & 1u);
    return (unsigned short)(r >> 16);
}

__device__ __forceinline__ unsigned pk2bf(float a, float b){
#if __has_builtin(__builtin_amdgcn_cvt_pk_bf16_f32)
    typedef __attribute__((ext_vector_type(2))) __bf16 bf2;
    bf2 r = __builtin_amdgcn_cvt_pk_bf16_f32(a, b);
    return *(unsigned*)&r;
#else
    return (unsigned)f2bf(a) | ((unsigned)f2bf(b) << 16);
#endif
}

__device__ __forceinline__ float fast_exp2(float x){
#if __has_builtin(__builtin_amdgcn_exp2f)
    return __builtin_amdgcn_exp2f(x);
#else
    return exp2f(x);
#endif
}

__device__ __forceinline__ float fast_rcp(float x){
#if __has_builtin(__builtin_amdgcn_rcpf)
    return __builtin_amdgcn_rcpf(x);
#else
    return 1.0f / x;
#endif
}

// ---------------- fused prep: range-dispatched over blockIdx.x (unchanged, passing) -------
__global__ void prep_all(const float* __restrict__ q, const float* __restrict__ k,
                         const float* __restrict__ v, const int* __restrict__ mask,
                         const float* __restrict__ W,
                         unsigned short* __restrict__ Qb, unsigned short* __restrict__ Kb,
                         unsigned short* __restrict__ Vt, unsigned short* __restrict__ Wb,
                         unsigned* __restrict__ Mb){
    __shared__ unsigned short tile[64*68];
    const int b = blockIdx.x, tid = threadIdx.x;
    if (b < 4096){
        const float SC = 0.045084220027780106f;   // log2(e)/32
        int base = (b*256 + tid) * 4;
        int e = base & (EMB - 1);
        int s = (base >> 10) & (S_LEN - 1);
        int n = base >> 21;
        int h = e >> 6, d = e & 63;
        int dst = ((n*NHEAD + h)*S_LEN + s)*DHEAD + d;
        float4 qv = *(const float4*)(q + base);
        float4 kv = *(const float4*)(k + base);
        uint2 qp, kp;
        qp.x = pk2bf(qv.x*SC, qv.y*SC);
        qp.y = pk2bf(qv.z*SC, qv.w*SC);
        kp.x = pk2bf(kv.x, kv.y);
        kp.y = pk2bf(kv.z, kv.w);
        *(uint2*)(Qb + dst) = qp;
        *(uint2*)(Kb + dst) = kp;
    } else if (b < 5120){
        int idx = b - 4096;
        int st = idx & 31, h = (idx >> 5) & 15, n = idx >> 9;
        int sbase = st * 64;
#pragma unroll
        for (int i = 0; i < 4; i++){
            int c = tid + i*256;
            int srow = c >> 4, c4 = (c & 15) * 4;
            float4 x = *(const float4*)(v + (n*S_LEN + sbase + srow)*EMB + h*DHEAD + c4);
            uint2 p;
            p.x = pk2bf(x.x, x.y);
            p.y = pk2bf(x.z, x.w);
            *(uint2*)&tile[srow*68 + c4] = p;
        }
        __syncthreads();
#pragma unroll
        for (int i = 0; i < 2; i++){
            int c = tid + i*256;
            int d = c >> 3, s8 = (c & 7) * 8;
            unsigned u0 = (unsigned)tile[(s8+0)*68 + d] | ((unsigned)tile[(s8+1)*68 + d] << 16);
            unsigned u1 = (unsigned)tile[(s8+2)*68 + d] | ((unsigned)tile[(s8+3)*68 + d] << 16);
            unsigned u2 = (unsigned)tile[(s8+4)*68 + d] | ((unsigned)tile[(s8+5)*68 + d] << 16);
            unsigned u3 = (unsigned)tile[(s8+6)*68 + d] | ((unsigned)tile[(s8+7)*68 + d] << 16);
            uint4 pk; pk.x = u0; pk.y = u1; pk.z = u2; pk.w = u3;
            *(uint4*)(Vt + ((n*NHEAD + h)*DHEAD + d)*S_LEN + sbase + s8) = pk;
        }
    } else if (b < 6144){
        int base = ((b - 5120)*256 + tid) * 4;
        float4 x = *(const float4*)(W + base);
        uint2 p;
        p.x = pk2bf(x.x, x.y);
        p.y = pk2bf(x.z, x.w);
        *(uint2*)(Wb + base) = p;
    } else {
        int u = (b - 6144)*256 + tid;                 // [0, 262144)
        const int4* m4 = (const int4*)mask + (size_t)u*8;
        unsigned w = 0;
#pragma unroll
        for (int i = 0; i < 8; i++){
            int4 m = m4[i];
            unsigned nib = (m.x ? 1u : 0u) | (m.y ? 2u : 0u) | (m.z ? 4u : 0u) | (m.w ? 8u : 0u);
            w |= nib << (i*4);
        }
        Mb[u] = w;
    }
}

// ---------------- flash attention: 32x32 MFMA core, permlane P-regroup, swizzled LDS -------
// Round-8 model: 56 MFMA/iter/wave at ~19.4 SIMD-cyc each (40 were K=16 half-FLOP PV ops) =
// the MfmaUtil-34.7% issue-bound wall. This version: QK as 2 32x32 k-tiles (8 MFMA), PV as
// 8 MFMA + 4 for L (B=ones) -> 20 MFMA/iter at 2x FLOP/issue. P goes from QK's C-layout
// (lane col=q; regs k=(r&3)+8(r>>2)+4hi) to the 32x32x16 A-frag (k=hi*8+j) with TWO
// v_permlane32_swap_b32 per k16-group: swap(a,b): a'={a.lo,b.lo->hi}, b'={a.hi->lo,b.hi}.
// LDS: 64-ushort pitch (128B: row base == 0 mod 32 banks) + chunk XOR (row&7) -> b128
// reads/writes at the structural floor (was 4-way on the 144B pitch).
__global__ __launch_bounds__(512, 2) void flash_attn(
    const unsigned short* __restrict__ Qb, const unsigned short* __restrict__ Kb,
    const unsigned short* __restrict__ Vt, const unsigned* __restrict__ Mb,
    unsigned short* __restrict__ Ab){
    __shared__ unsigned short Kt[2][64*64];
    __shared__ unsigned short Vl[2][64*64];
    __shared__ uint2 mlut[16];

    const int tid = threadIdx.x;
    if (tid < 16){
        uint2 e;
        e.x = ((tid & 1) ? 0xFFFFu : 0u) | ((tid & 2) ? 0xFFFF0000u : 0u);
        e.y = ((tid & 4) ? 0xFFFFu : 0u) | ((tid & 8) ? 0xFFFF0000u : 0u);
        mlut[tid] = e;
    }

    // XCD-aware remap: flat [0,256); each XCD owns 4 (n,h) slices x 8 qt-blocks.
    const int flat = blockIdx.x + (blockIdx.y << 3);  // grid (8, 32)
    const int xcd = flat & 7, idx = flat >> 3;
    const int qt = idx & 7;
    const int sl = xcd + ((idx >> 3) << 3);
    const int h = sl & 15, n = sl >> 4;

    const int wave = tid >> 6, lane = tid & 63;
    const int l31 = lane & 31, hi = lane >> 5;
    const int qbase = qt*256 + wave*32;
    const int q = qbase + l31;

    const unsigned short* Qh = Qb + (n*NHEAD + h)*S_LEN*DHEAD;
    const unsigned short* Kh = Kb + (n*NHEAD + h)*S_LEN*DHEAD;
    const unsigned short* Vh = Vt + (n*NHEAD + h)*DHEAD*S_LEN;
    const unsigned* mr = Mb + (size_t)(n*S_LEN + q)*(S_LEN/32);

    // staging: 512 threads, one uint4 of K + one of V each, swizzled dest
    const int srow = tid >> 3, schunk = tid & 7;
    const int sdst = srow*64 + ((schunk ^ (srow & 7)) * 8);   // ushort offset

    bf16x8 Qf[4];   // B-frags: col=q (l31), d = g*16 + hi*8 + j
#pragma unroll
    for (int g = 0; g < 4; g++)
        Qf[g] = *(const bf16x8*)(Qh + q*DHEAD + g*16 + hi*8);

    f32x16 accO0 = (f32x16)0.0f, accO1 = (f32x16)0.0f, accL = (f32x16)0.0f;
    const short onev = 0x3F80;
    const bf16x8 ones8 = {onev,onev,onev,onev,onev,onev,onev,onev};

    uint4 kpre = *(const uint4*)(Kh + srow*DHEAD + schunk*8);
    uint4 vpre = *(const uint4*)(Vh + srow*S_LEN + schunk*8);

    int c = 0;
    for (int kb = 0; kb < S_LEN; kb += 64){
        *(uint4*)&Kt[c][sdst] = kpre;
        *(uint4*)&Vl[c][sdst] = vpre;
        __syncthreads();   // nothing in flight: barrier drain free (round-8 fix)
        if (kb + 64 < S_LEN){
            kpre = *(const uint4*)(Kh + (kb + 64 + srow)*DHEAD + schunk*8);
            vpre = *(const uint4*)(Vh + srow*S_LEN + kb + 64 + schunk*8);
        }
        uint2 mw = *(const uint2*)(mr + (kb >> 5));   // 64 mask bits for this lane's q-row

        // QK: E[k][q] per tile t (k rows t*32+l31), contraction d via 4 g-steps
        f32x16 e0 = (f32x16)0.0f, e1 = (f32x16)0.0f;
#pragma unroll
        for (int g = 0; g < 4; g++){
            const int ch = g*2 + hi;
            const int r0 = l31, r1 = 32 + l31;
            bf16x8 kf0 = *(const bf16x8*)&Kt[c][r0*64 + ((ch ^ (r0 & 7))*8)];
            bf16x8 kf1 = *(const bf16x8*)&Kt[c][r1*64 + ((ch ^ (r1 & 7))*8)];
            e0 = MFMA32(kf0, Qf[g], e0);
            e1 = MFMA32(kf1, Qf[g], e1);
        }

        // softmax + mask + pack. reg r of tile t: k = t*32 + 8*(r>>2) + 4*hi + (r&3).
        // nibble s covers k(8s+4hi..+3) -> pairs align with pk2bf(p[4s],p[4s+1]) etc.
        unsigned pw[2][4][2];
#pragma unroll
        for (int t = 0; t < 2; t++){
            const f32x16 ev = t ? e1 : e0;
            unsigned sh = (t ? mw.y : mw.x) >> (4*hi);
#pragma unroll
            for (int s = 0; s < 4; s++){
                uint2 m = mlut[(sh >> (8*s)) & 0xFu];
                float p0 = fast_exp2(ev[4*s+0]);
                float p1 = fast_exp2(ev[4*s+1]);
                float p2 = fast_exp2(ev[4*s+2]);
                float p3 = fast_exp2(ev[4*s+3]);
                pw[t][s][0] = pk2bf(p0, p1) & m.x;
                pw[t][s][1] = pk2bf(p2, p3) & m.y;
            }
        }

        // PV + L: per k16-group (t,gg): permlane-regroup P into the A-frag, then 3 MFMA.
#pragma unroll
        for (int t = 0; t < 2; t++){
#pragma unroll
            for (int gg = 0; gg < 2; gg++){
                unsigned a0 = pw[t][2*gg][0],   b0 = pw[t][2*gg+1][0];
                unsigned a1 = pw[t][2*gg][1],   b1 = pw[t][2*gg+1][1];
                asm volatile("v_permlane32_swap_b32 %0, %1" : "+v"(a0), "+v"(b0));
                asm volatile("v_permlane32_swap_b32 %0, %1" : "+v"(a1), "+v"(b1));
                uint4 af; af.x = a0; af.y = a1; af.z = b0; af.w = b1;
                bf16x8 Pa = *(bf16x8*)&af;
                const int kg = t*2 + gg;            // k16-group: s-cols kg*16 + hi*8
                const int ch = kg*2 + hi;
                const int d0 = l31, d1 = 32 + l31;
                bf16x8 vf0 = *(const bf16x8*)&Vl[c][d0*64 + ((ch ^ (d0 & 7))*8)];
                bf16x8 vf1 = *(const bf16x8*)&Vl[c][d1*64 + ((ch ^ (d1 & 7))*8)];
                accO0 = MFMA32(Pa, vf0, accO0);
                accO1 = MFMA32(Pa, vf1, accO1);
                accL  = MFMA32(Pa, ones8, accL);
            }
        }
        c ^= 1;
    }

    // epilogue: accL rows share the C-layout row pattern with accO -> normalize per reg,
    // store bf16 O rows (d = dtile*32 + l31).
#pragma unroll
    for (int r = 0; r < 16; r++){
        float inv = fast_rcp(accL[r]);
        int qrow = qbase + (r & 3) + 8*(r >> 2) + 4*hi;
        unsigned short* dst = Ab + (size_t)(n*S_LEN + qrow)*EMB + h*DHEAD + l31;
        dst[0]  = f2bf(accO0[r]*inv);
        dst[32] = f2bf(accO1[r]*inv);
    }
}

// ---------------- output GEMM: direct-reg, no LDS, no barriers (unchanged, passing) -------
__global__ __launch_bounds__(256, 4) void gemm_out(
    const unsigned short* __restrict__ Ab, const unsigned short* __restrict__ W,
    const float* __restrict__ bias, float* __restrict__ out){
    const int flat = blockIdx.x + (blockIdx.y << 4);  // [0,1024)
    const int xcd = flat & 7, idx = flat >> 3;
    const int nb = idx & 15, mb = xcd*8 + (idx >> 4);
    const int tid = threadIdx.x;
    const int wave = tid >> 6, lane = tid & 63, il = lane & 15, quad = lane >> 4;
    const int wm = wave & 1, wn = wave >> 1;
    const int mbase = mb*64, nbase = nb*64;

    f32x4 acc[2][2];
#pragma unroll
    for (int i = 0; i < 2; i++)
#pragma unroll
        for (int j = 0; j < 2; j++) acc[i][j] = (f32x4){0.f,0.f,0.f,0.f};

    const unsigned short* A0 = Ab + (size_t)(mbase + wm*32 + il)*EMB + quad*8;
    const unsigned short* W0 = W  + (size_t)(nbase + wn*32 + il)*EMB + quad*8;

#pragma unroll
    for (int kb = 0; kb < EMB; kb += 64){
        bf16x8 Af[2][2], Wf[2][2];
#pragma unroll
        for (int mt = 0; mt < 2; mt++)
#pragma unroll
            for (int ks = 0; ks < 2; ks++)
                Af[mt][ks] = *(const bf16x8*)(A0 + (size_t)mt*16*EMB + kb + ks*32);
#pragma unroll
        for (int nt = 0; nt < 2; nt++)
#pragma unroll
            for (int ks = 0; ks < 2; ks++)
                Wf[nt][ks] = *(const bf16x8*)(W0 + (size_t)nt*16*EMB + kb + ks*32);
#pragma unroll
        for (int ks = 0; ks < 2; ks++)
#pragma unroll
            for (int mt = 0; mt < 2; mt++)
#pragma unroll
                for (int nt = 0; nt < 2; nt++)
                    acc[mt][nt] = __builtin_amdgcn_mfma_f32_16x16x32_bf16(Af[mt][ks], Wf[nt][ks], acc[mt][nt], 0, 0, 0);
    }

    float bb[2];
#pragma unroll
    for (int nt = 0; nt < 2; nt++) bb[nt] = bias[nbase + wn*32 + nt*16 + il];
#pragma unroll
    for (int mt = 0; mt < 2; mt++)
#pragma unroll
        for (int r = 0; r < 4; r++){
            int row = mbase + wm*32 + mt*16 + quad*4 + r;
            float* dst = &out[(size_t)row*EMB + nbase + wn*32 + il];
#pragma unroll
            for (int nt = 0; nt < 2; nt++)
                dst[nt*16] = acc[mt][nt][r] + bb[nt];
        }
}

extern "C" void kernel_launch(void* const* d_in, const int* in_sizes, int n_in,
                              void* d_out, int out_size, void* d_ws, size_t ws_size,
                              hipStream_t stream){
    const float* values = (const float*)d_in[0];
    const float* keys   = (const float*)d_in[1];
    const float* query  = (const float*)d_in[2];
    const int*   mask   = (const int*)d_in[3];
    const float* W_fc   = (const float*)d_in[4];
    const float* b_fc   = (const float*)d_in[5];
    float* out = (float*)d_out;

    char* ws = (char*)d_ws;
    unsigned short* Qb  = (unsigned short*)(ws);                        // 8 MiB
    unsigned short* Kb  = (unsigned short*)(ws + (8ull  << 20));        // 8 MiB
    unsigned short* Vtb = (unsigned short*)(ws + (16ull << 20));        // 8 MiB
    unsigned short* Wb  = (unsigned short*)(ws + (24ull << 20));        // 2 MiB
    unsigned*       Mb  = (unsigned*)      (ws + (26ull << 20));        // 1 MiB (bit-packed mask)
    unsigned short* Ab  = (unsigned short*)(ws + (27ull << 20));        // 8 MiB normalized bf16 O

    prep_all  <<<7168, 256, 0, stream>>>(query, keys, values, mask, W_fc,
                                         Qb, Kb, Vtb, Wb, Mb);
    flash_attn<<<dim3(8, 32), 512, 0, stream>>>(Qb, Kb, Vtb, Mb, Ab);
    gemm_out  <<<dim3(16, 64), 256, 0, stream>>>(Ab, Wb, b_fc, out);
}